// Round 2
// 1904.739 us; speedup vs baseline: 1.1221x; 1.1221x over previous
//
#include <hip/hip_runtime.h>
#include <cmath>

// Problem constants (fixed by the reference's setup_inputs)
constexpr int kF   = 512;   // features
constexpr int kT   = 9;     // teams
constexpr int kS   = 9;     // slots
constexpr int kNP  = 81;    // T*S
constexpr int kH1  = 32;
constexpr int kH2  = 64;
constexpr int kBLK = 576;   // 9 waves; wave t owns team t

// Workspace layout (floats) — rewritten by prep every launch (ws is poisoned)
constexpr int WS_W1P  = 0;                       // [t][f][o]  T*F*H1 = 147456
constexpr int WS_W2P  = WS_W1P + kT * kF * kH1;  // [t][o]     T*H1   = 288
constexpr int WS_MW1P = WS_W2P + kT * kH1;       // [f][o]     F*H2   = 32768
constexpr int WS_MW2P = WS_MW1P + kF * kH2;      // [o]        H2     = 64
constexpr int WS_TOTAL = WS_MW2P + kH2;          // 180576 floats

// Pass-B chunking
constexpr int kFCH = 64;                 // f per chunk
constexpr int kNCH = kF / kFCH;          // 8 chunks

// Shared memory layout (floats)
constexpr int SM_XBUF = 0;                    // [64][81] = 5184 ; phase-2 overlay pm[9][9][64]
constexpr int SM_TO   = SM_XBUF + kFCH*kNP;   // 5184: team_out [t][f] = 4608
constexpr int SM_Q    = SM_TO + kT*kF;        // 9792: q [t][12]
constexpr int SM_TQ   = SM_Q + kT*12;         // 9900
constexpr int SM_MS   = SM_TQ + 12;           // 9912
constexpr int SM_MW   = SM_MS + 12;           // 9924
constexpr int SM_SCALE= SM_MW + 12;           // 9936
constexpr int SM_FLOATS = SM_SCALE + 4;       // 9940 floats = 38.8 KB -> 3 blocks/CU (thread-capped)

typedef float vf4 __attribute__((ext_vector_type(4)));

__device__ __forceinline__ float pnorm1(float x, float g, float b) {
    float r = fmodf(x, 7.0f);
    if (r < 0.0f) r += 7.0f;
    return g * ((r - 3.5f) / 3.5f) + b;
}

// ---------------- prep: fold all apply_rot's into the weight matrices ----------------
__global__ void prep_kernel(const float* __restrict__ W1, const float* __restrict__ ang1,
                            const float* __restrict__ W2, const float* __restrict__ ang2,
                            const float* __restrict__ mW1, const float* __restrict__ mang1,
                            const float* __restrict__ mW2, const float* __restrict__ mang2,
                            float* __restrict__ ws) {
    int i = blockIdx.x * 256 + threadIdx.x;
    if (i < kT * kF * kH1) {
        int t = i / (kF * kH1); int r = i - t * (kF * kH1);
        int f = r / kH1;        int o = r - f * kH1;
        float v;
        if (f >= 4) {
            v = W1[(t * kH1 + o) * kF + f];
        } else {
            int p = f >> 1; float a = ang1[t * 2 + p];
            float c = cosf(a), s = sinf(a);
            float w0 = W1[(t * kH1 + o) * kF + 2 * p];
            float w1 = W1[(t * kH1 + o) * kF + 2 * p + 1];
            v = (f & 1) ? (-s * w0 + c * w1) : (c * w0 + s * w1);
        }
        ws[WS_W1P + (t * kF + f) * kH1 + o] = v;
    }
    int j = i - kT * kF * kH1;
    if (j >= 0 && j < kT * kH1) {
        int t = j / kH1, o = j - (j / kH1) * kH1;
        float v;
        if (o >= 4) {
            v = W2[t * kH1 + o];
        } else {
            int p = o >> 1; float a = ang2[t * 2 + p];
            float c = cosf(a), s = sinf(a);
            float w0 = W2[t * kH1 + 2 * p], w1 = W2[t * kH1 + 2 * p + 1];
            v = (o & 1) ? (-s * w0 + c * w1) : (c * w0 + s * w1);
        }
        ws[WS_W2P + j] = v;
    }
    int k = j - kT * kH1;
    if (k >= 0 && k < kF * kH2) {
        int f = k / kH2, o = k - (k / kH2) * kH2;
        float v;
        if (f >= 8) {
            v = mW1[o * kF + f];
        } else {
            int p = f >> 1; float a = mang1[p];
            float c = cosf(a), s = sinf(a);
            float w0 = mW1[o * kF + 2 * p], w1 = mW1[o * kF + 2 * p + 1];
            v = (f & 1) ? (-s * w0 + c * w1) : (c * w0 + s * w1);
        }
        ws[WS_MW1P + f * kH2 + o] = v;
    }
    int m = k - kF * kH2;
    if (m >= 0 && m < kH2) {
        float v;
        if (m >= 4) {
            v = mW2[m];
        } else {
            int p = m >> 1; float a = mang2[p];
            float c = cosf(a), s = sinf(a);
            float w0 = mW2[2 * p], w1 = mW2[2 * p + 1];
            v = (m & 1) ? (-s * w0 + c * w1) : (c * w0 + s * w1);
        }
        ws[WS_MW2P + m] = v;
    }
}

// ---------------- main: one block per batch element b, 9 waves = 9 teams ----------------
__global__ __launch_bounds__(kBLK) void scorer_kernel(
    const float* __restrict__ path,  const float* __restrict__ b1,
    const float* __restrict__ gamma1, const float* __restrict__ beta1,
    const float* __restrict__ b2v,   const float* __restrict__ mb1,
    const float* __restrict__ mgamma, const float* __restrict__ mbeta,
    const float* __restrict__ mb2,   const float* __restrict__ c_comm,
    const float* __restrict__ c_res, const float* __restrict__ c_int,
    const float* __restrict__ ws,    float* __restrict__ out) {
    __shared__ float sm[SM_FLOATS];
    const int tid = threadIdx.x;
    const int b   = blockIdx.x;
    const int wv  = tid >> 6;      // wave index == team index
    const int ln  = tid & 63;      // lane
    const int o   = ln & 31;       // h1 output column
    const int fh  = ln >> 5;       // f-half (0: f<256, 1: f>=256)
    const float* W1p  = ws + WS_W1P;
    const float* W2p  = ws + WS_W2P;
    const float* mW1p = ws + WS_MW1P;
    const float* mW2p = ws + WS_MW2P;
    const size_t pbase = (size_t)b * (kF * kNP);

    // ======== Phase 0 (barrier-free, per-wave): h1 GEMM -> pnorm -> scores -> softmax ========
    // lane (fh,o) accumulates h[t=wv, s=0..8, o] over its 256-f half.
    float acc[kS];
    #pragma unroll
    for (int s = 0; s < kS; ++s) acc[s] = 0.f;
    {
        const float* xp = path + pbase + (size_t)(fh * (kF / 2)) * kNP + wv * kS;
        const float* wp = W1p + ((size_t)wv * kF + fh * (kF / 2)) * kH1 + o;
        #pragma unroll 2
        for (int f = 0; f < kF / 2; ++f) {
            float w = wp[f * kH1];                 // coalesced 128B per half-wave, L2-hot
            const float* xr = xp + f * kNP;        // 9 floats, broadcast across 32 lanes
            #pragma unroll
            for (int s = 0; s < kS; ++s) acc[s] += xr[s] * w;
        }
    }
    // fold f-halves (xor lane bit 5)
    #pragma unroll
    for (int s = 0; s < kS; ++s) acc[s] += __shfl_xor(acc[s], 32);

    // bias + pnorm + W2 contraction, then reduce over o (lane bits 0..4)
    {
        const float bb = b1[wv * kH1 + o];
        const float gg = gamma1[wv * kH1 + o];
        const float be = beta1[wv * kH1 + o];
        const float w2 = W2p[wv * kH1 + o];
        float con[kS];
        #pragma unroll
        for (int s = 0; s < kS; ++s) con[s] = pnorm1(acc[s] + bb, gg, be) * w2;
        #pragma unroll
        for (int s = 0; s < kS; ++s) {
            con[s] += __shfl_xor(con[s], 1);
            con[s] += __shfl_xor(con[s], 2);
            con[s] += __shfl_xor(con[s], 4);
            con[s] += __shfl_xor(con[s], 8);
            con[s] += __shfl_xor(con[s], 16);
        }
        const float b2t = b2v[wv];
        float sc[kS];
        #pragma unroll
        for (int s = 0; s < kS; ++s) sc[s] = con[s] + b2t;
        float mx = sc[0];
        #pragma unroll
        for (int s = 1; s < kS; ++s) mx = fmaxf(mx, sc[s]);
        float e[kS]; float sum = 0.f;
        #pragma unroll
        for (int s = 0; s < kS; ++s) { e[s] = expf(sc[s] - mx); sum += e[s]; }
        const float inv = 1.f / sum;
        if (ln == 0) {
            float tqv = 0.f;
            #pragma unroll
            for (int s = 0; s < kS; ++s) {
                float qv = e[s] * inv;
                sm[SM_Q + wv * 12 + s] = qv;
                tqv += qv;
            }
            sm[SM_TQ + wv] = tqv * (1.f / 9.f);
        }
    }
    __syncthreads();   // q complete for all teams; xbuf about to be used

    // ======== Phase 1: team_out[t][f] = sum_s x[f,t,s]*q[t,s], chunked LDS staging ========
    float qr[kS];
    #pragma unroll
    for (int s = 0; s < kS; ++s) qr[s] = sm[SM_Q + wv * 12 + s];

    for (int ch = 0; ch < kNCH; ++ch) {
        if (ch) __syncthreads();                    // previous chunk consumed
        const float* g = path + pbase + (size_t)ch * (kFCH * kNP);
        // stage 64 f-rows = 5184 floats = 1296 float4, coalesced (L2/L3-hot re-read)
        for (int i = tid; i < (kFCH * kNP) / 4; i += kBLK) {
            ((vf4*)(sm + SM_XBUF))[i] = ((const vf4*)g)[i];
        }
        __syncthreads();
        // thread (t=wv, f_local=ln): 9 LDS reads, stride 81 across lanes -> conflict-free
        const float* xp = sm + SM_XBUF + ln * kNP + wv * kS;
        float v = 0.f;
        #pragma unroll
        for (int s = 0; s < kS; ++s) v += xp[s] * qr[s];
        sm[SM_TO + wv * kF + ch * kFCH + ln] = v;
    }
    __syncthreads();   // team_out complete; xbuf free for overlay

    // ======== Phase 2: master GEMM, wave-parallel over f-slices ========
    {
        const int f0 = wv * 57;
        const int f1 = (wv == 8) ? kF : f0 + 57;    // 8*57 + 56 = 512
        float am[kT];
        #pragma unroll
        for (int t = 0; t < kT; ++t) am[t] = 0.f;
        for (int f = f0; f < f1; ++f) {
            float w = mW1p[f * kH2 + ln];            // coalesced 256B per wave, read once/block
            #pragma unroll
            for (int t = 0; t < kT; ++t) am[t] += sm[SM_TO + t * kF + f] * w;
        }
        #pragma unroll
        for (int t = 0; t < kT; ++t) sm[SM_XBUF + (wv * kT + t) * 64 + ln] = am[t];
    }
    __syncthreads();
    {
        // thread (t=wv, o=ln): combine 9 f-slice partials, pnorm, mW2, in-wave reduce
        float h = mb1[ln];
        #pragma unroll
        for (int w = 0; w < kT; ++w) h += sm[SM_XBUF + (w * kT + wv) * 64 + ln];
        float val = pnorm1(h, mgamma[ln], mbeta[ln]) * mW2p[ln];
        val += __shfl_xor(val, 1);
        val += __shfl_xor(val, 2);
        val += __shfl_xor(val, 4);
        val += __shfl_xor(val, 8);
        val += __shfl_xor(val, 16);
        val += __shfl_xor(val, 32);
        if (ln == 0) sm[SM_MS + wv] = val + mb2[0];
    }
    __syncthreads();
    if (tid == 0) {
        float mx = -1e30f;
        for (int t = 0; t < kT; ++t) mx = fmaxf(mx, sm[SM_MS + t]);
        float e[kT]; float sum = 0.f;
        for (int t = 0; t < kT; ++t) { e[t] = expf(sm[SM_MS + t] - mx); sum += e[t]; }
        float inv = 1.f / sum;
        for (int t = 0; t < kT; ++t) sm[SM_MW + t] = e[t] * inv;
        // penalty from runtime coeffs (tq == 1/9 mathematically; compute numerically)
        float mean = 0.f;
        for (int t = 0; t < kT; ++t) mean += sm[SM_TQ + t];
        mean *= (1.f / 9.f);
        float var = 0.f;
        for (int t = 0; t < kT; ++t) { float d = sm[SM_TQ + t] - mean; var += d * d; }
        var *= (1.f / 8.f);   // ddof=1
        float nv = var / (mean * mean + 1e-8f);
        float total = c_comm[0] * (kT * (kT - 1) / 2) + c_res[0] * kT +
                      c_int[0] * kT * (1.f + nv);
        float pen = fminf(total, 0.5f);
        sm[SM_SCALE] = 1.f - pen;
    }
    __syncthreads();

    // ======== Phase 3: final[f] = sum_t to[t][f]*mw[t] * scale ========
    {
        float mwr[kT];
        #pragma unroll
        for (int t = 0; t < kT; ++t) mwr[t] = sm[SM_MW + t];
        const float scl = sm[SM_SCALE];
        if (tid < kF) {
            float v = 0.f;
            #pragma unroll
            for (int t = 0; t < kT; ++t) v += sm[SM_TO + t * kF + tid] * mwr[t];
            out[(size_t)b * kF + tid] = v * scl;
        }
    }
}

extern "C" void kernel_launch(void* const* d_in, const int* in_sizes, int n_in,
                              void* d_out, int out_size, void* d_ws, size_t ws_size,
                              hipStream_t stream) {
    const float* path   = (const float*)d_in[0];
    const float* W1     = (const float*)d_in[1];
    const float* b1     = (const float*)d_in[2];
    const float* ang1   = (const float*)d_in[3];
    const float* gamma1 = (const float*)d_in[4];
    const float* beta1  = (const float*)d_in[5];
    const float* W2     = (const float*)d_in[6];
    const float* b2     = (const float*)d_in[7];
    const float* ang2   = (const float*)d_in[8];
    const float* mW1    = (const float*)d_in[9];
    const float* mb1    = (const float*)d_in[10];
    const float* mang1  = (const float*)d_in[11];
    const float* mgamma = (const float*)d_in[12];
    const float* mbeta  = (const float*)d_in[13];
    const float* mW2    = (const float*)d_in[14];
    const float* mb2    = (const float*)d_in[15];
    const float* mang2  = (const float*)d_in[16];
    const float* c_comm = (const float*)d_in[17];
    const float* c_res  = (const float*)d_in[18];
    const float* c_int  = (const float*)d_in[19];
    float* ws = (float*)d_ws;
    float* outp = (float*)d_out;

    const int Bn = in_sizes[0] / (kF * kNP);   // 4096

    prep_kernel<<<(WS_TOTAL + 255) / 256, 256, 0, stream>>>(
        W1, ang1, W2, ang2, mW1, mang1, mW2, mang2, ws);
    scorer_kernel<<<Bn, kBLK, 0, stream>>>(
        path, b1, gamma1, beta1, b2, mb1, mgamma, mbeta, mb2,
        c_comm, c_res, c_int, ws, outp);
}

// Round 3
// 1595.310 us; speedup vs baseline: 1.3397x; 1.1940x over previous
//
#include <hip/hip_runtime.h>
#include <cmath>

// Problem constants (fixed by the reference's setup_inputs)
constexpr int kF   = 512;   // features
constexpr int kT   = 9;     // teams
constexpr int kS   = 9;     // slots
constexpr int kNP  = 81;    // T*S
constexpr int kH1  = 32;
constexpr int kH2  = 64;
constexpr int kBLK = 576;   // 9 waves; wave t owns team t

// Workspace layout (floats) — rewritten by prep every launch (ws is poisoned)
constexpr int WS_W1P  = 0;                       // [t][f][o]  T*F*H1 = 147456
constexpr int WS_W2P  = WS_W1P + kT * kF * kH1;  // [t][o]     T*H1   = 288
constexpr int WS_MW1P = WS_W2P + kT * kH1;       // [f][o]     F*H2   = 32768
constexpr int WS_MW2P = WS_MW1P + kF * kH2;      // [o]        H2     = 64
constexpr int WS_TOTAL = WS_MW2P + kH2;          // 180576 floats

// Chunked x staging (shared by phase 0 and phase 1)
constexpr int kCHF  = 32;              // f per chunk
constexpr int kNCH  = kF / kCHF;       // 16 chunks
constexpr int kCHFL = kCHF * kNP;      // 2592 floats per chunk (identity-linear in LDS)
constexpr int kCHV4 = kCHFL / 4;       // 648 float4 loads per chunk

// Shared memory layout (floats)
constexpr int SM_XB0 = 0;                     // x chunk buffer 0 [32][81]
constexpr int SM_XB1 = kCHFL;                 // 2592: x chunk buffer 1
constexpr int SM_TO  = 2 * kCHFL;             // 5184: team_out [t][f] = 4608
constexpr int SM_TQ  = SM_TO + kT * kF;       // 9792
constexpr int SM_MS  = SM_TQ + 12;            // 9804
constexpr int SM_MW  = SM_MS + 12;            // 9816
constexpr int SM_SCALE = SM_MW + 12;          // 9828
constexpr int SM_FLOATS = SM_SCALE + 4;       // 9832 floats = 39.3 KB -> 4 blocks LDS-cap, 3 thread-cap
// Phase-2 overlay: partials pm[9][9][64] = 5184 floats in [0, 5184) (both x buffers, dead then)

typedef float vf4 __attribute__((ext_vector_type(4)));

__device__ __forceinline__ float pnorm1(float x, float g, float b) {
    float r = fmodf(x, 7.0f);
    if (r < 0.0f) r += 7.0f;
    return g * ((r - 3.5f) / 3.5f) + b;
}

// Async coalesced global->LDS staging of one 2592-float chunk (identity layout).
// LDS dest is lane-linear (base + i*16B with i = tid + k*kBLK), satisfying the
// wave-uniform-base + lane*size hardware constraint of global_load_lds.
__device__ __forceinline__ void stage_chunk(const float* __restrict__ g,
                                            float* lds_base, int tid) {
    for (int i = tid; i < kCHV4; i += kBLK) {
        __builtin_amdgcn_global_load_lds(
            (const __attribute__((address_space(1))) void*)(g + i * 4),
            (__attribute__((address_space(3))) void*)(lds_base + i * 4),
            16, 0, 0);
    }
}

// ---------------- prep: fold all apply_rot's into the weight matrices ----------------
__global__ void prep_kernel(const float* __restrict__ W1, const float* __restrict__ ang1,
                            const float* __restrict__ W2, const float* __restrict__ ang2,
                            const float* __restrict__ mW1, const float* __restrict__ mang1,
                            const float* __restrict__ mW2, const float* __restrict__ mang2,
                            float* __restrict__ ws) {
    int i = blockIdx.x * 256 + threadIdx.x;
    if (i < kT * kF * kH1) {
        int t = i / (kF * kH1); int r = i - t * (kF * kH1);
        int f = r / kH1;        int o = r - f * kH1;
        float v;
        if (f >= 4) {
            v = W1[(t * kH1 + o) * kF + f];
        } else {
            int p = f >> 1; float a = ang1[t * 2 + p];
            float c = cosf(a), s = sinf(a);
            float w0 = W1[(t * kH1 + o) * kF + 2 * p];
            float w1 = W1[(t * kH1 + o) * kF + 2 * p + 1];
            v = (f & 1) ? (-s * w0 + c * w1) : (c * w0 + s * w1);
        }
        ws[WS_W1P + (t * kF + f) * kH1 + o] = v;
    }
    int j = i - kT * kF * kH1;
    if (j >= 0 && j < kT * kH1) {
        int t = j / kH1, o = j - (j / kH1) * kH1;
        float v;
        if (o >= 4) {
            v = W2[t * kH1 + o];
        } else {
            int p = o >> 1; float a = ang2[t * 2 + p];
            float c = cosf(a), s = sinf(a);
            float w0 = W2[t * kH1 + 2 * p], w1 = W2[t * kH1 + 2 * p + 1];
            v = (o & 1) ? (-s * w0 + c * w1) : (c * w0 + s * w1);
        }
        ws[WS_W2P + j] = v;
    }
    int k = j - kT * kH1;
    if (k >= 0 && k < kF * kH2) {
        int f = k / kH2, o = k - (k / kH2) * kH2;
        float v;
        if (f >= 8) {
            v = mW1[o * kF + f];
        } else {
            int p = f >> 1; float a = mang1[p];
            float c = cosf(a), s = sinf(a);
            float w0 = mW1[o * kF + 2 * p], w1 = mW1[o * kF + 2 * p + 1];
            v = (f & 1) ? (-s * w0 + c * w1) : (c * w0 + s * w1);
        }
        ws[WS_MW1P + f * kH2 + o] = v;
    }
    int m = k - kF * kH2;
    if (m >= 0 && m < kH2) {
        float v;
        if (m >= 4) {
            v = mW2[m];
        } else {
            int p = m >> 1; float a = mang2[p];
            float c = cosf(a), s = sinf(a);
            float w0 = mW2[2 * p], w1 = mW2[2 * p + 1];
            v = (m & 1) ? (-s * w0 + c * w1) : (c * w0 + s * w1);
        }
        ws[WS_MW2P + m] = v;
    }
}

// ---------------- main: one block per batch element b, 9 waves = 9 teams ----------------
__global__ __launch_bounds__(kBLK) void scorer_kernel(
    const float* __restrict__ path,  const float* __restrict__ b1,
    const float* __restrict__ gamma1, const float* __restrict__ beta1,
    const float* __restrict__ b2v,   const float* __restrict__ mb1,
    const float* __restrict__ mgamma, const float* __restrict__ mbeta,
    const float* __restrict__ mb2,   const float* __restrict__ c_comm,
    const float* __restrict__ c_res, const float* __restrict__ c_int,
    const float* __restrict__ ws,    float* __restrict__ out) {
    __shared__ float sm[SM_FLOATS];
    const int tid = threadIdx.x;
    const int b   = blockIdx.x;
    const int wv  = tid >> 6;      // wave index == team index
    const int ln  = tid & 63;      // lane
    const float* W1p  = ws + WS_W1P;
    const float* W2p  = ws + WS_W2P;
    const float* mW1p = ws + WS_MW1P;
    const float* mW2p = ws + WS_MW2P;
    const size_t pbase = (size_t)b * (kF * kNP);
    const float* xrow = path + pbase;

    // ======== Phase 0: h1 GEMM via dbuf LDS chunks; in-wave reduce; softmax ========
    // lane mapping: og = ln&7 (4 o's each: o = og*4+j), fl = ln>>3 (f stripe mod 8).
    // W1p float4 load: addr = fl*128B + og*16B -> 1024B contiguous per wave. x from LDS,
    // 8 distinct rows broadcast x8 (banks 17*fl mod 32: all distinct) -> conflict-free.
    const int og = ln & 7;
    const int fl = ln >> 3;
    vf4 acc[kS];
    #pragma unroll
    for (int s = 0; s < kS; ++s) acc[s] = (vf4){0.f, 0.f, 0.f, 0.f};

    stage_chunk(xrow, sm + SM_XB0, tid);              // prologue: chunk 0 in flight
    for (int ch = 0; ch < kNCH; ++ch) {
        __syncthreads();                              // chunk ch landed (vmcnt drain); prev compute done
        if (ch + 1 < kNCH)                            // prefetch next chunk into other buffer
            stage_chunk(xrow + (ch + 1) * kCHFL,
                        sm + (((ch + 1) & 1) ? SM_XB1 : SM_XB0), tid);
        const float* bufp  = sm + ((ch & 1) ? SM_XB1 : SM_XB0);
        const float* wbase = W1p + ((size_t)(wv * kF + ch * kCHF)) * kH1 + og * 4;
        #pragma unroll
        for (int k = 0; k < kCHF / 8; ++k) {
            const int flc = k * 8 + fl;
            const vf4 w = *(const vf4*)(wbase + flc * kH1);
            const float* xr = bufp + flc * kNP + wv * kS;
            #pragma unroll
            for (int s = 0; s < kS; ++s) {
                const float xv = xr[s];
                acc[s].x += xv * w.x; acc[s].y += xv * w.y;
                acc[s].z += xv * w.z; acc[s].w += xv * w.w;
            }
        }
    }

    // fold the 8 f-stripes (lane bits 3,4,5)
    #pragma unroll
    for (int s = 0; s < kS; ++s) {
        #pragma unroll
        for (int m = 8; m <= 32; m <<= 1) {
            acc[s].x += __shfl_xor(acc[s].x, m);
            acc[s].y += __shfl_xor(acc[s].y, m);
            acc[s].z += __shfl_xor(acc[s].z, m);
            acc[s].w += __shfl_xor(acc[s].w, m);
        }
    }

    // bias + pnorm + W2 contraction over this lane's 4 o's, reduce over og (bits 0..2)
    float qr[kS];
    {
        const int ob = wv * kH1 + og * 4;
        const vf4 bb = *(const vf4*)(b1 + ob);
        const vf4 gg = *(const vf4*)(gamma1 + ob);
        const vf4 be = *(const vf4*)(beta1 + ob);
        const vf4 w2 = *(const vf4*)(W2p + ob);
        float con[kS];
        #pragma unroll
        for (int s = 0; s < kS; ++s) {
            con[s] = pnorm1(acc[s].x + bb.x, gg.x, be.x) * w2.x +
                     pnorm1(acc[s].y + bb.y, gg.y, be.y) * w2.y +
                     pnorm1(acc[s].z + bb.z, gg.z, be.z) * w2.z +
                     pnorm1(acc[s].w + bb.w, gg.w, be.w) * w2.w;
        }
        #pragma unroll
        for (int s = 0; s < kS; ++s) {
            con[s] += __shfl_xor(con[s], 1);
            con[s] += __shfl_xor(con[s], 2);
            con[s] += __shfl_xor(con[s], 4);
        }
        const float b2t = b2v[wv];
        float mx = con[0] + b2t;
        #pragma unroll
        for (int s = 1; s < kS; ++s) mx = fmaxf(mx, con[s] + b2t);
        float sum = 0.f;
        #pragma unroll
        for (int s = 0; s < kS; ++s) { qr[s] = expf(con[s] + b2t - mx); sum += qr[s]; }
        const float inv = 1.f / sum;
        float tqv = 0.f;
        #pragma unroll
        for (int s = 0; s < kS; ++s) { qr[s] *= inv; tqv += qr[s]; }
        if (ln == 0) sm[SM_TQ + wv] = tqv * (1.f / 9.f);   // q itself stays in registers
    }

    // ======== Phase 1: team_out[t][f] = sum_s x[f][t*9+s]*q[t][s], same dbuf machinery ========
    // lane: fP = ln&31 (f within chunk), sh = ln>>5 (s-halves 0..4 / 4..8 with qh[0]=0 on sh=1)
    const int fP = ln & 31, sh = ln >> 5;
    float qh[5];
    {
        const int sbase = sh * 4;
        #pragma unroll
        for (int jq = 0; jq < 5; ++jq) qh[jq] = qr[sbase + jq];
        if (sh == 1) qh[0] = 0.f;
    }
    stage_chunk(xrow, sm + SM_XB0, tid);   // safe: XB0 last read at phase-0 chunk 14, all waves past it
    for (int ch = 0; ch < kNCH; ++ch) {
        __syncthreads();
        if (ch + 1 < kNCH)
            stage_chunk(xrow + (ch + 1) * kCHFL,
                        sm + (((ch + 1) & 1) ? SM_XB1 : SM_XB0), tid);
        const float* bufp = sm + ((ch & 1) ? SM_XB1 : SM_XB0);
        const float* xr = bufp + fP * kNP + wv * kS + sh * 4;
        float v = xr[0] * qh[0] + xr[1] * qh[1] + xr[2] * qh[2] +
                  xr[3] * qh[3] + xr[4] * qh[4];
        v += __shfl_xor(v, 32);
        if (sh == 0) sm[SM_TO + wv * kF + ch * kCHF + fP] = v;
    }
    __syncthreads();   // team_out complete; x buffers free for overlay

    // ======== Phase 2: master GEMM, wave-parallel over f-slices ========
    {
        const int f0 = wv * 57;
        const int f1 = (wv == 8) ? kF : f0 + 57;    // 8*57 + 56 = 512
        float am[kT];
        #pragma unroll
        for (int t = 0; t < kT; ++t) am[t] = 0.f;
        for (int f = f0; f < f1; ++f) {
            float w = mW1p[f * kH2 + ln];            // coalesced 256B per wave, L2-hot
            #pragma unroll
            for (int t = 0; t < kT; ++t) am[t] += sm[SM_TO + t * kF + f] * w;
        }
        #pragma unroll
        for (int t = 0; t < kT; ++t) sm[SM_XB0 + (wv * kT + t) * 64 + ln] = am[t];
    }
    __syncthreads();
    {
        // thread (t=wv, o=ln): combine 9 f-slice partials, pnorm, mW2, in-wave reduce
        float h = mb1[ln];
        #pragma unroll
        for (int w = 0; w < kT; ++w) h += sm[SM_XB0 + (w * kT + wv) * 64 + ln];
        float val = pnorm1(h, mgamma[ln], mbeta[ln]) * mW2p[ln];
        val += __shfl_xor(val, 1);
        val += __shfl_xor(val, 2);
        val += __shfl_xor(val, 4);
        val += __shfl_xor(val, 8);
        val += __shfl_xor(val, 16);
        val += __shfl_xor(val, 32);
        if (ln == 0) sm[SM_MS + wv] = val + mb2[0];
    }
    __syncthreads();
    if (tid == 0) {
        float mx = -1e30f;
        for (int t = 0; t < kT; ++t) mx = fmaxf(mx, sm[SM_MS + t]);
        float e[kT]; float sum = 0.f;
        for (int t = 0; t < kT; ++t) { e[t] = expf(sm[SM_MS + t] - mx); sum += e[t]; }
        float inv = 1.f / sum;
        for (int t = 0; t < kT; ++t) sm[SM_MW + t] = e[t] * inv;
        // penalty from runtime coeffs (tq == 1/9 mathematically; compute numerically)
        float mean = 0.f;
        for (int t = 0; t < kT; ++t) mean += sm[SM_TQ + t];
        mean *= (1.f / 9.f);
        float var = 0.f;
        for (int t = 0; t < kT; ++t) { float d = sm[SM_TQ + t] - mean; var += d * d; }
        var *= (1.f / 8.f);   // ddof=1
        float nv = var / (mean * mean + 1e-8f);
        float total = c_comm[0] * (kT * (kT - 1) / 2) + c_res[0] * kT +
                      c_int[0] * kT * (1.f + nv);
        float pen = fminf(total, 0.5f);
        sm[SM_SCALE] = 1.f - pen;
    }
    __syncthreads();

    // ======== Phase 3: final[f] = sum_t to[t][f]*mw[t] * scale ========
    {
        float mwr[kT];
        #pragma unroll
        for (int t = 0; t < kT; ++t) mwr[t] = sm[SM_MW + t];
        const float scl = sm[SM_SCALE];
        if (tid < kF) {
            float v = 0.f;
            #pragma unroll
            for (int t = 0; t < kT; ++t) v += sm[SM_TO + t * kF + tid] * mwr[t];
            out[(size_t)b * kF + tid] = v * scl;
        }
    }
}

extern "C" void kernel_launch(void* const* d_in, const int* in_sizes, int n_in,
                              void* d_out, int out_size, void* d_ws, size_t ws_size,
                              hipStream_t stream) {
    const float* path   = (const float*)d_in[0];
    const float* W1     = (const float*)d_in[1];
    const float* b1     = (const float*)d_in[2];
    const float* ang1   = (const float*)d_in[3];
    const float* gamma1 = (const float*)d_in[4];
    const float* beta1  = (const float*)d_in[5];
    const float* W2     = (const float*)d_in[6];
    const float* b2     = (const float*)d_in[7];
    const float* ang2   = (const float*)d_in[8];
    const float* mW1    = (const float*)d_in[9];
    const float* mb1    = (const float*)d_in[10];
    const float* mang1  = (const float*)d_in[11];
    const float* mgamma = (const float*)d_in[12];
    const float* mbeta  = (const float*)d_in[13];
    const float* mW2    = (const float*)d_in[14];
    const float* mb2    = (const float*)d_in[15];
    const float* mang2  = (const float*)d_in[16];
    const float* c_comm = (const float*)d_in[17];
    const float* c_res  = (const float*)d_in[18];
    const float* c_int  = (const float*)d_in[19];
    float* ws = (float*)d_ws;
    float* outp = (float*)d_out;

    const int Bn = in_sizes[0] / (kF * kNP);   // 4096

    prep_kernel<<<(WS_TOTAL + 255) / 256, 256, 0, stream>>>(
        W1, ang1, W2, ang2, mW1, mang1, mW2, mang2, ws);
    scorer_kernel<<<Bn, kBLK, 0, stream>>>(
        path, b1, gamma1, beta1, b2, mb1, mgamma, mbeta, mb2,
        c_comm, c_res, c_int, ws, outp);
}